// Round 13
// baseline (419.226 us; speedup 1.0000x reference)
//
#include <hip/hip_runtime.h>
#include <hip/hip_bf16.h>
#include <stdint.h>

// AWQ GEMM: out[2048,11008](f32) = x[2048,4096](f32,f16-valued) @ dequant4(...) + bias
// Round 13: clean 2-blocks/CU test. gfx950 unified VGPR+AGPR file gates waves:
// r8/r12 = 112 arch + 64 acc = 176/wave -> 2 waves/SIMD -> 1 block/CU (Occ 21%).
// This round: BM=128 (areg[2], acc[2][4]) -> ~96 arch + 32 acc = ~128 total ->
// 4 waves/SIMD -> 2 independent blocks/CU (LDS 48KB not limiting), with
// launch_bounds(512,2) (the non-spilling setting; r9/r11's (512,4) forced 64
// VGPR and spilled). Everything else = r12: f16 fast-dequant, XOR swizzles,
// A single-buf + B double-buf (stage_B pre-barrier), XCD-bijective grid.

constexpr int IN_F   = 4096;
constexpr int OUT_F  = 11008;
constexpr int PCOLS  = OUT_F / 8;   // 1376
constexpr int BM = 128, BN = 128, BK = 64;
constexpr int NKT    = IN_F / BK;   // 64
constexpr int NTILES = OUT_F / BN;  // 86
constexpr int ABYTES = BM * BK * 2; // 16384 (single buffer)
constexpr int BBYTES = BN * BK * 2; // 16384 (x2 buffers)

typedef _Float16 h2 __attribute__((ext_vector_type(2)));
typedef _Float16 h8 __attribute__((ext_vector_type(8)));
typedef float f32x4  __attribute__((ext_vector_type(4)));

__device__ __forceinline__ h2 pkh2(float a, float b) {
    return __builtin_bit_cast(h2, __builtin_amdgcn_cvt_pkrtz(a, b));
}
__device__ __forceinline__ unsigned int pk2(float a, float b) {
    return __builtin_bit_cast(unsigned int, __builtin_amdgcn_cvt_pkrtz(a, b));
}

__global__ __launch_bounds__(512, 2)
void awq_gemm_kernel(const float* __restrict__ X,
                     const int*   __restrict__ QW,
                     const int*   __restrict__ QZ,
                     const float* __restrict__ S,
                     const float* __restrict__ BIAS,
                     float*       __restrict__ O)
{
    // A [128 rows][128B] at 0 (single buf); B buf b: [128 cols][128B] at 16384+b*16384
    // A: k-octet o of row r at 16B slot o^(r&7)
    // B: k-octet o of col n at 16B slot o^(n&7)^((n>>3)&7)
    __shared__ alignas(16) unsigned char smem[ABYTES + 2 * BBYTES];  // 49152

    const int t    = threadIdx.x;
    const int lane = t & 63;
    const int w    = t >> 6;      // 0..7
    const int wm   = w >> 1;      // 0..3 (row block of 32)
    const int wn   = w & 1;       // 0..1 (col block of 64)
    const int l15 = lane & 15, l45 = lane >> 4, l7 = lane & 7, l3 = (lane >> 3) & 1;

    // XCD-bijective mapping: XCD x (=bid&7) owns mtiles {2x,2x+1}, sweeps ntiles.
    const int bid   = blockIdx.x;            // 0..1375 = 8*172
    const int idx   = bid >> 3;              // 0..171
    const int mtile = (bid & 7) * 2 + idx / NTILES;
    const int ntile = idx % NTILES;
    const int m0 = mtile * BM;
    const int n0 = ntile * BN;
    const int P0 = n0 >> 3;

    // ---- A staging: thread covers rows {t>>3, (t>>3)+64}, k-octet t&7 ----
    const int arow = t >> 3;              // 0..63
    const int aoct = t & 7;
    const int aphys = aoct ^ (arow & 7);  // +64 preserves row&7
    const float* Xb = X + (size_t)(m0 + arow) * IN_F + aoct * 8;

    float4 areg[2][2];
    auto load_A = [&](int kt) {
#pragma unroll
        for (int i = 0; i < 2; ++i) {
            const float* p = Xb + (size_t)i * 64 * IN_F + kt * BK;
            areg[i][0] = *(const float4*)(p);
            areg[i][1] = *(const float4*)(p + 4);
        }
    };
    auto write_A = [&]() {
        unsigned char* ab = smem;
#pragma unroll
        for (int i = 0; i < 2; ++i) {
            uint4 v;
            v.x = pk2(areg[i][0].x, areg[i][0].y);
            v.y = pk2(areg[i][0].z, areg[i][0].w);
            v.z = pk2(areg[i][1].x, areg[i][1].y);
            v.w = pk2(areg[i][1].z, areg[i][1].w);
            *(uint4*)(ab + (i * 64 + arow) * 128 + aphys * 16) = v;
        }
    };

    // ---- B staging: thread covers packed col pcol = t&15, k-pair 2kd, 2kd+1 (kd = t>>4) ----
    const int pcol = t & 15;
    const int kd   = t >> 4;         // 0..31
    const int pc7  = pcol & 7;
    const int ob   = kd >> 2;        // k-octet
    const int sub  = (kd & 3) * 4;   // byte offset within 16B slot
    const int* qwb = QW + (size_t)(2 * kd) * PCOLS + P0 + pcol;
    const unsigned int* qzc = (const unsigned int*)QZ + P0 + pcol;
    const float* scol = S + n0 + pcol * 8;

    constexpr int SH[8]  = {0, 16, 4, 20, 8, 24, 12, 28}; // shift of logical nibble j
    constexpr int JLO[4] = {0, 4, 1, 5};                  // low-nibble j of byte b

    h2 spk[8], zpk[8];
    unsigned int zraw_n; float4 sv0, sv1;
    unsigned int raw0, raw1;

    auto load_group = [&](int g) {
        zraw_n = qzc[(size_t)g * PCOLS];
        sv0 = *(const float4*)(scol + (size_t)g * OUT_F);
        sv1 = *(const float4*)(scol + (size_t)g * OUT_F + 4);
    };
    auto compute_group = [&]() {
        const float sf[8] = {sv0.x, sv0.y, sv0.z, sv0.w, sv1.x, sv1.y, sv1.z, sv1.w};
#pragma unroll
        for (int j = 0; j < 8; ++j) {
            float zb = 1024.0f + (float)((zraw_n >> SH[j]) & 15u);  // exact in f16
            spk[j] = pkh2(sf[j], sf[j]);
            zpk[j] = pkh2(zb, zb);
        }
    };
    auto load_raws = [&](int kt) {
        const size_t off = (size_t)kt * BK * PCOLS;
        raw0 = (unsigned int)qwb[off];
        raw1 = (unsigned int)qwb[off + PCOLS];
    };
    auto stage_B = [&](int buf) {
        unsigned char* bb = smem + ABYTES + buf * BBYTES;
#pragma unroll
        for (int b = 0; b < 4; ++b) {
            const int jl = JLO[b], jh = jl + 2;
            // byte b of raw0 -> dst byte0, byte b of raw1 -> dst byte2 (others masked)
            unsigned int d  = __builtin_amdgcn_perm(raw1, raw0,
                                 (unsigned int)(((4 + b) << 16) | b));
            unsigned int lo = (d & 0x000F000Fu) | 0x64006400u;         // (1024+q) pair, j=jl
            unsigned int hi = ((d >> 4) & 0x000F000Fu) | 0x64006400u;  // j=jh
            // exact sub (both exact ints in f16), then single f16 rounding on mul
            h2 wl = (__builtin_bit_cast(h2, lo) - zpk[jl]) * spk[jl];
            h2 wh = (__builtin_bit_cast(h2, hi) - zpk[jh]) * spk[jh];
            const int nl = pcol * 8 + jl, nh = pcol * 8 + jh;
            *(unsigned int*)(bb + nl * 128 + ((ob ^ jl ^ pc7) * 16) + sub) =
                __builtin_bit_cast(unsigned int, wl);
            *(unsigned int*)(bb + nh * 128 + ((ob ^ jh ^ pc7) * 16) + sub) =
                __builtin_bit_cast(unsigned int, wh);
        }
    };

    f32x4 acc[2][4];
#pragma unroll
    for (int mi = 0; mi < 2; ++mi)
#pragma unroll
        for (int ni = 0; ni < 4; ++ni)
            acc[mi][ni] = f32x4{0.f, 0.f, 0.f, 0.f};

    auto compute_tile = [&](int buf) {
        const unsigned char* ab = smem;
        const unsigned char* bb = smem + ABYTES + buf * BBYTES;
#pragma unroll
        for (int ks = 0; ks < 2; ++ks) {
            h8 a[2], bf[4];
#pragma unroll
            for (int mi = 0; mi < 2; ++mi) {
                int off = (wm * 32 + mi * 16 + l15) * 128
                        + (((ks * 4 + l45) ^ l7) * 16);          // row&7 == l7
                a[mi] = *(const h8*)(ab + off);
            }
#pragma unroll
            for (int ni = 0; ni < 4; ++ni) {
                int off = (wn * 64 + ni * 16 + l15) * 128
                        + ((((ks * 4 + l45) ^ l7 ^ l3) ^ (2 * ni)) * 16); // n&7==l7
                bf[ni] = *(const h8*)(bb + off);
            }
#pragma unroll
            for (int mi = 0; mi < 2; ++mi)
#pragma unroll
                for (int ni = 0; ni < 4; ++ni)
                    acc[mi][ni] = __builtin_amdgcn_mfma_f32_16x16x32_f16(
                        a[mi], bf[ni], acc[mi][ni], 0, 0, 0);
        }
    };

    // ---- prologue: stage tile 0 (A buf + B buf0) ----
    load_A(0);
    load_raws(0);
    load_group(0);
    compute_group();
    write_A();
    stage_B(0);
    __syncthreads();

    // ---- main loop ----
    // [issue global loads k+1] [compute k (A-buf, B-buf[cur])]
    // [dequant+write B k+1 -> B-buf[cur^1]] (pre-barrier: disjoint from B[cur] reads)
    // [sync: A reads done] [write_A k+1] [sync]
#pragma unroll 2
    for (int kt = 0; kt < NKT; ++kt) {
        const int cur = kt & 1;
        if (kt + 1 < NKT) {
            load_A(kt + 1);                    // issue-early (T14)
            load_raws(kt + 1);
            if (((kt + 1) & 1) == 0) load_group((kt + 1) >> 1);
        }
        compute_tile(cur);
        if (kt + 1 < NKT) {
            if (((kt + 1) & 1) == 0) compute_group();
            stage_B(cur ^ 1);                  // other B buffer: no barrier needed
        }
        __syncthreads();                       // A-buf reads complete
        if (kt + 1 < NKT) {
            write_A();                         // overwrite single A buffer
        }
        __syncthreads();                       // A writes visible
    }

    // ---- epilogue: bias + f32 store (C/D: col=lane&15, row=(lane>>4)*4+reg) ----
    const int orow0 = m0 + wm * 32 + l45 * 4;
    const int ocol0 = n0 + wn * 64 + l15;
    float bv[4];
#pragma unroll
    for (int ni = 0; ni < 4; ++ni)
        bv[ni] = BIAS[ocol0 + ni * 16];
#pragma unroll
    for (int mi = 0; mi < 2; ++mi)
#pragma unroll
        for (int ni = 0; ni < 4; ++ni)
#pragma unroll
            for (int r = 0; r < 4; ++r) {
                int row = orow0 + mi * 16 + r;
                int col = ocol0 + ni * 16;
                O[(size_t)row * OUT_F + col] = acc[mi][ni][r] + bv[ni];
            }
}

extern "C" void kernel_launch(void* const* d_in, const int* in_sizes, int n_in,
                              void* d_out, int out_size, void* d_ws, size_t ws_size,
                              hipStream_t stream) {
    const float* X  = (const float*)d_in[0];
    const int*   QW = (const int*)d_in[1];
    const int*   QZ = (const int*)d_in[2];
    const float* S  = (const float*)d_in[3];
    const float* Bi = (const float*)d_in[4];
    float*       O  = (float*)d_out;

    dim3 grid(16 * NTILES);   // 1376
    dim3 block(512);
    awq_gemm_kernel<<<grid, block, 0, stream>>>(X, QW, QZ, S, Bi, O);
}

// Round 14
// 237.882 us; speedup vs baseline: 1.7623x; 1.7623x over previous
//
#include <hip/hip_runtime.h>
#include <hip/hip_bf16.h>
#include <stdint.h>

// AWQ GEMM: out[2048,11008](f32) = x[2048,4096](f32,f16-valued) @ dequant4(...) + bias
// Round 14: two-kernel plan.
//  K1 convert: X f32 -> f16, PRE-SWIZZLED tile-ready layout in d_ws (16 MB):
//      Xsw[row][kt][c] (16B chunks, c=0..7) = X[row][kt*64 + (c^(row&7))*8 .. +8]
//  K2 GEMM: BM=256 r12 body, but A staged via global_load_lds DMA straight from
//      Xsw (linear LDS dest == swizzled content, rule 21). Eliminates areg,
//      write_A, the second barrier, and the vmcnt-at-use stall; A-DMA for kt+1
//      issues at top of iter kt and drains at the single end-of-iter barrier
//      (full-iteration latency cover = T4 mechanism, r1/r2 validated this path).
// Fallback: if ws_size < 16 MB, run the r12 single-kernel version.

constexpr int TOKENS = 2048;
constexpr int IN_F   = 4096;
constexpr int OUT_F  = 11008;
constexpr int PCOLS  = OUT_F / 8;   // 1376
constexpr int BM = 256, BN = 128, BK = 64;
constexpr int NKT    = IN_F / BK;   // 64
constexpr int NTILES = OUT_F / BN;  // 86
constexpr int ABYTES = BM * BK * 2; // 32768 per buffer
constexpr int BBYTES = BN * BK * 2; // 16384 per buffer
constexpr int LDSTOT = 2 * ABYTES + 2 * BBYTES; // 98304
constexpr size_t XSW_BYTES = (size_t)TOKENS * IN_F * 2; // 16 MB

typedef _Float16 h2 __attribute__((ext_vector_type(2)));
typedef _Float16 h8 __attribute__((ext_vector_type(8)));
typedef float f32x4  __attribute__((ext_vector_type(4)));

__device__ __forceinline__ h2 pkh2(float a, float b) {
    return __builtin_bit_cast(h2, __builtin_amdgcn_cvt_pkrtz(a, b));
}
__device__ __forceinline__ unsigned int pk2(float a, float b) {
    return __builtin_bit_cast(unsigned int, __builtin_amdgcn_cvt_pkrtz(a, b));
}
__device__ __forceinline__ void gld_lds16(const void* g, void* l) {
    __builtin_amdgcn_global_load_lds(
        (const __attribute__((address_space(1))) void*)g,
        (__attribute__((address_space(3))) void*)l,
        16, 0, 0);
}

// ---------------- K1: convert + pre-swizzle X ----------------
__global__ __launch_bounds__(256)
void x_convert_kernel(const float* __restrict__ X, unsigned short* __restrict__ Xsw)
{
    // one thread per 16B output chunk; g = row*512 + kt*8 + c
    const int g   = blockIdx.x * 256 + threadIdx.x;   // 0 .. 2048*512-1
    const int c   = g & 7;
    const int kt  = (g >> 3) & 63;
    const int row = g >> 9;
    const float* src = X + (size_t)row * IN_F + kt * 64 + ((c ^ (row & 7)) * 8);
    float4 v0 = *(const float4*)(src);
    float4 v1 = *(const float4*)(src + 4);
    uint4 u;
    u.x = pk2(v0.x, v0.y);
    u.y = pk2(v0.z, v0.w);
    u.z = pk2(v1.x, v1.y);
    u.w = pk2(v1.z, v1.w);
    *(uint4*)(Xsw + (size_t)g * 8) = u;
}

// ---------------- K2: main GEMM (A via DMA from Xsw) ----------------
__global__ __launch_bounds__(512, 2)
void awq_gemm_dma_kernel(const unsigned short* __restrict__ Xsw,
                         const int*   __restrict__ QW,
                         const int*   __restrict__ QZ,
                         const float* __restrict__ S,
                         const float* __restrict__ BIAS,
                         float*       __restrict__ O)
{
    // A buf b: [256 rows][128B] at b*32768 ; B buf b: [128 cols][128B] at 65536+b*16384
    // A: slot c of row r holds k-octet c^(r&7)   (from Xsw layout)
    // B: k-octet o of col n at 16B slot o^(n&7)^((n>>3)&7)
    extern __shared__ unsigned char smem[];

    const int t    = threadIdx.x;
    const int lane = t & 63;
    const int w    = t >> 6;      // 0..7
    const int wm   = w >> 1;      // 0..3 (row block of 64)
    const int wn   = w & 1;       // 0..1 (col block of 64)
    const int l15 = lane & 15, l45 = lane >> 4, l7 = lane & 7, l3 = (lane >> 3) & 1;

    // XCD mapping: XCD x (= bid&7) owns mtile x; sweeps all 86 ntiles. 688 = 8*86.
    const int bid   = blockIdx.x;
    const int mtile = bid & 7;
    const int ntile = bid >> 3;
    const int m0 = mtile * BM;
    const int n0 = ntile * BN;
    const int P0 = n0 >> 3;

    // ---- A staging via DMA: thread t covers row (t>>3)+64i, 16B chunk t&7 ----
    // src per lane: Xsw byte ((row_g*64 + kt)*8 + (t&7))*16 ; dest linear lane*16.
    const unsigned char* XswB = (const unsigned char*)Xsw;
    auto stage_A_dma = [&](int buf, int kt) {
        unsigned char* ab = smem + buf * ABYTES;
#pragma unroll
        for (int i = 0; i < 4; ++i) {
            const int row_g = m0 + i * 64 + (t >> 3);
            const unsigned char* src = XswB + (((size_t)row_g * 64 + kt) * 8 + (t & 7)) * 16;
            gld_lds16(src, ab + i * 8192 + w * 1024);
        }
    };

    // ---- B staging: thread covers packed col pcol = t&15, k-pair 2kd, 2kd+1 (kd = t>>4) ----
    const int pcol = t & 15;
    const int kd   = t >> 4;         // 0..31
    const int pc7  = pcol & 7;
    const int ob   = kd >> 2;        // k-octet
    const int sub  = (kd & 3) * 4;   // byte offset within 16B slot
    const int* qwb = QW + (size_t)(2 * kd) * PCOLS + P0 + pcol;
    const unsigned int* qzc = (const unsigned int*)QZ + P0 + pcol;
    const float* scol = S + n0 + pcol * 8;

    constexpr int SH[8]  = {0, 16, 4, 20, 8, 24, 12, 28}; // shift of logical nibble j
    constexpr int JLO[4] = {0, 4, 1, 5};                  // low-nibble j of byte b

    h2 spk[8], zpk[8];
    unsigned int zraw_n; float4 sv0, sv1;
    unsigned int raw0, raw1;

    auto load_group = [&](int g) {
        zraw_n = qzc[(size_t)g * PCOLS];
        sv0 = *(const float4*)(scol + (size_t)g * OUT_F);
        sv1 = *(const float4*)(scol + (size_t)g * OUT_F + 4);
    };
    auto compute_group = [&]() {
        const float sf[8] = {sv0.x, sv0.y, sv0.z, sv0.w, sv1.x, sv1.y, sv1.z, sv1.w};
#pragma unroll
        for (int j = 0; j < 8; ++j) {
            float zb = 1024.0f + (float)((zraw_n >> SH[j]) & 15u);  // exact in f16
            spk[j] = pkh2(sf[j], sf[j]);
            zpk[j] = pkh2(zb, zb);
        }
    };
    auto load_raws = [&](int kt) {
        const size_t off = (size_t)kt * BK * PCOLS;
        raw0 = (unsigned int)qwb[off];
        raw1 = (unsigned int)qwb[off + PCOLS];
    };
    auto stage_B = [&](int buf) {
        unsigned char* bb = smem + 2 * ABYTES + buf * BBYTES;
#pragma unroll
        for (int b = 0; b < 4; ++b) {
            const int jl = JLO[b], jh = jl + 2;
            unsigned int d  = __builtin_amdgcn_perm(raw1, raw0,
                                 (unsigned int)(((4 + b) << 16) | b));
            unsigned int lo = (d & 0x000F000Fu) | 0x64006400u;         // (1024+q), j=jl
            unsigned int hi = ((d >> 4) & 0x000F000Fu) | 0x64006400u;  // j=jh
            h2 wl = (__builtin_bit_cast(h2, lo) - zpk[jl]) * spk[jl];  // exact sub, 1 rounding
            h2 wh = (__builtin_bit_cast(h2, hi) - zpk[jh]) * spk[jh];
            const int nl = pcol * 8 + jl, nh = pcol * 8 + jh;
            *(unsigned int*)(bb + nl * 128 + ((ob ^ jl ^ pc7) * 16) + sub) =
                __builtin_bit_cast(unsigned int, wl);
            *(unsigned int*)(bb + nh * 128 + ((ob ^ jh ^ pc7) * 16) + sub) =
                __builtin_bit_cast(unsigned int, wh);
        }
    };

    f32x4 acc[4][4];
#pragma unroll
    for (int mi = 0; mi < 4; ++mi)
#pragma unroll
        for (int ni = 0; ni < 4; ++ni)
            acc[mi][ni] = f32x4{0.f, 0.f, 0.f, 0.f};

    auto compute_tile = [&](int buf) {
        const unsigned char* ab = smem + buf * ABYTES;
        const unsigned char* bb = smem + 2 * ABYTES + buf * BBYTES;
#pragma unroll
        for (int ks = 0; ks < 2; ++ks) {
            h8 a[4], bf[4];
#pragma unroll
            for (int mi = 0; mi < 4; ++mi) {
                int off = (wm * 64 + mi * 16 + l15) * 128
                        + (((ks * 4 + l45) ^ l7) * 16);          // row&7 == l7
                a[mi] = *(const h8*)(ab + off);
            }
#pragma unroll
            for (int ni = 0; ni < 4; ++ni) {
                int off = (wn * 64 + ni * 16 + l15) * 128
                        + ((((ks * 4 + l45) ^ l7 ^ l3) ^ (2 * ni)) * 16); // n&7==l7
                bf[ni] = *(const h8*)(bb + off);
            }
#pragma unroll
            for (int mi = 0; mi < 4; ++mi)
#pragma unroll
                for (int ni = 0; ni < 4; ++ni)
                    acc[mi][ni] = __builtin_amdgcn_mfma_f32_16x16x32_f16(
                        a[mi], bf[ni], acc[mi][ni], 0, 0, 0);
        }
    };

    // ---- prologue: stage tile 0 into buf 0 ----
    stage_A_dma(0, 0);
    load_raws(0);
    load_group(0);
    compute_group();
    stage_B(0);
    __syncthreads();   // drains DMA (vmcnt) + ds_writes (lgkmcnt)

    // ---- main loop: ONE barrier per iter ----
    // [A-DMA kt+1 -> bufA^1] [raws kt+1 -> reg] [compute kt] [dequant+write B kt+1 -> bufB^1] [sync]
#pragma unroll 2
    for (int kt = 0; kt < NKT; ++kt) {
        const int cur = kt & 1;
        if (kt + 1 < NKT) {
            stage_A_dma(cur ^ 1, kt + 1);      // async DMA, drains at end-of-iter barrier
            load_raws(kt + 1);
            if (((kt + 1) & 1) == 0) load_group((kt + 1) >> 1);
        }
        compute_tile(cur);
        if (kt + 1 < NKT) {
            if (((kt + 1) & 1) == 0) compute_group();
            stage_B(cur ^ 1);
        }
        __syncthreads();
    }

    // ---- epilogue: bias + f32 store (C/D: col=lane&15, row=(lane>>4)*4+reg) ----
    const int orow0 = m0 + wm * 64 + l45 * 4;
    const int ocol0 = n0 + wn * 64 + l15;
    float bv[4];
#pragma unroll
    for (int ni = 0; ni < 4; ++ni)
        bv[ni] = BIAS[ocol0 + ni * 16];
#pragma unroll
    for (int mi = 0; mi < 4; ++mi)
#pragma unroll
        for (int ni = 0; ni < 4; ++ni)
#pragma unroll
            for (int r = 0; r < 4; ++r) {
                int row = orow0 + mi * 16 + r;
                int col = ocol0 + ni * 16;
                O[(size_t)row * OUT_F + col] = acc[mi][ni][r] + bv[ni];
            }
}

// ---------------- fallback: r12 kernel (ws too small) ----------------
__global__ __launch_bounds__(512, 2)
void awq_gemm_fb_kernel(const float* __restrict__ X,
                        const int*   __restrict__ QW,
                        const int*   __restrict__ QZ,
                        const float* __restrict__ S,
                        const float* __restrict__ BIAS,
                        float*       __restrict__ O)
{
    __shared__ alignas(16) unsigned char smem[ABYTES + 2 * BBYTES];

    const int t    = threadIdx.x;
    const int lane = t & 63;
    const int w    = t >> 6;
    const int wm   = w >> 1;
    const int wn   = w & 1;
    const int l15 = lane & 15, l45 = lane >> 4, l7 = lane & 7, l3 = (lane >> 3) & 1;

    const int bid   = blockIdx.x;
    const int mtile = bid & 7;
    const int ntile = bid >> 3;
    const int m0 = mtile * BM;
    const int n0 = ntile * BN;
    const int P0 = n0 >> 3;

    const int arow = t >> 3;
    const int aoct = t & 7;
    const int aphys = aoct ^ (arow & 7);
    const float* Xb = X + (size_t)(m0 + arow) * IN_F + aoct * 8;

    float4 areg[4][2];
    auto load_A = [&](int kt) {
#pragma unroll
        for (int i = 0; i < 4; ++i) {
            const float* p = Xb + (size_t)i * 64 * IN_F + kt * BK;
            areg[i][0] = *(const float4*)(p);
            areg[i][1] = *(const float4*)(p + 4);
        }
    };
    auto write_A = [&]() {
        unsigned char* ab = smem;
#pragma unroll
        for (int i = 0; i < 4; ++i) {
            uint4 v;
            v.x = pk2(areg[i][0].x, areg[i][0].y);
            v.y = pk2(areg[i][0].z, areg[i][0].w);
            v.z = pk2(areg[i][1].x, areg[i][1].y);
            v.w = pk2(areg[i][1].z, areg[i][1].w);
            *(uint4*)(ab + (i * 64 + arow) * 128 + aphys * 16) = v;
        }
    };

    const int pcol = t & 15;
    const int kd   = t >> 4;
    const int pc7  = pcol & 7;
    const int ob   = kd >> 2;
    const int sub  = (kd & 3) * 4;
    const int* qwb = QW + (size_t)(2 * kd) * PCOLS + P0 + pcol;
    const unsigned int* qzc = (const unsigned int*)QZ + P0 + pcol;
    const float* scol = S + n0 + pcol * 8;

    constexpr int SH[8]  = {0, 16, 4, 20, 8, 24, 12, 28};
    constexpr int JLO[4] = {0, 4, 1, 5};

    h2 spk[8], zpk[8];
    unsigned int zraw_n; float4 sv0, sv1;
    unsigned int raw0, raw1;

    auto load_group = [&](int g) {
        zraw_n = qzc[(size_t)g * PCOLS];
        sv0 = *(const float4*)(scol + (size_t)g * OUT_F);
        sv1 = *(const float4*)(scol + (size_t)g * OUT_F + 4);
    };
    auto compute_group = [&]() {
        const float sf[8] = {sv0.x, sv0.y, sv0.z, sv0.w, sv1.x, sv1.y, sv1.z, sv1.w};
#pragma unroll
        for (int j = 0; j < 8; ++j) {
            float zb = 1024.0f + (float)((zraw_n >> SH[j]) & 15u);
            spk[j] = pkh2(sf[j], sf[j]);
            zpk[j] = pkh2(zb, zb);
        }
    };
    auto load_raws = [&](int kt) {
        const size_t off = (size_t)kt * BK * PCOLS;
        raw0 = (unsigned int)qwb[off];
        raw1 = (unsigned int)qwb[off + PCOLS];
    };
    auto stage_B = [&](int buf) {
        unsigned char* bb = smem + ABYTES + buf * BBYTES;
#pragma unroll
        for (int b = 0; b < 4; ++b) {
            const int jl = JLO[b], jh = jl + 2;
            unsigned int d  = __builtin_amdgcn_perm(raw1, raw0,
                                 (unsigned int)(((4 + b) << 16) | b));
            unsigned int lo = (d & 0x000F000Fu) | 0x64006400u;
            unsigned int hi = ((d >> 4) & 0x000F000Fu) | 0x64006400u;
            h2 wl = (__builtin_bit_cast(h2, lo) - zpk[jl]) * spk[jl];
            h2 wh = (__builtin_bit_cast(h2, hi) - zpk[jh]) * spk[jh];
            const int nl = pcol * 8 + jl, nh = pcol * 8 + jh;
            *(unsigned int*)(bb + nl * 128 + ((ob ^ jl ^ pc7) * 16) + sub) =
                __builtin_bit_cast(unsigned int, wl);
            *(unsigned int*)(bb + nh * 128 + ((ob ^ jh ^ pc7) * 16) + sub) =
                __builtin_bit_cast(unsigned int, wh);
        }
    };

    f32x4 acc[4][4];
#pragma unroll
    for (int mi = 0; mi < 4; ++mi)
#pragma unroll
        for (int ni = 0; ni < 4; ++ni)
            acc[mi][ni] = f32x4{0.f, 0.f, 0.f, 0.f};

    auto compute_tile = [&](int buf) {
        const unsigned char* ab = smem;
        const unsigned char* bb = smem + ABYTES + buf * BBYTES;
#pragma unroll
        for (int ks = 0; ks < 2; ++ks) {
            h8 a[4], bf[4];
#pragma unroll
            for (int mi = 0; mi < 4; ++mi) {
                int off = (wm * 64 + mi * 16 + l15) * 128
                        + (((ks * 4 + l45) ^ l7) * 16);
                a[mi] = *(const h8*)(ab + off);
            }
#pragma unroll
            for (int ni = 0; ni < 4; ++ni) {
                int off = (wn * 64 + ni * 16 + l15) * 128
                        + ((((ks * 4 + l45) ^ l7 ^ l3) ^ (2 * ni)) * 16);
                bf[ni] = *(const h8*)(bb + off);
            }
#pragma unroll
            for (int mi = 0; mi < 4; ++mi)
#pragma unroll
                for (int ni = 0; ni < 4; ++ni)
                    acc[mi][ni] = __builtin_amdgcn_mfma_f32_16x16x32_f16(
                        a[mi], bf[ni], acc[mi][ni], 0, 0, 0);
        }
    };

    load_A(0);
    load_raws(0);
    load_group(0);
    compute_group();
    write_A();
    stage_B(0);
    __syncthreads();

#pragma unroll 2
    for (int kt = 0; kt < NKT; ++kt) {
        const int cur = kt & 1;
        if (kt + 1 < NKT) {
            load_A(kt + 1);
            load_raws(kt + 1);
            if (((kt + 1) & 1) == 0) load_group((kt + 1) >> 1);
        }
        compute_tile(cur);
        if (kt + 1 < NKT) {
            if (((kt + 1) & 1) == 0) compute_group();
            stage_B(cur ^ 1);
        }
        __syncthreads();
        if (kt + 1 < NKT) write_A();
        __syncthreads();
    }

    const int orow0 = m0 + wm * 64 + l45 * 4;
    const int ocol0 = n0 + wn * 64 + l15;
    float bv[4];
#pragma unroll
    for (int ni = 0; ni < 4; ++ni)
        bv[ni] = BIAS[ocol0 + ni * 16];
#pragma unroll
    for (int mi = 0; mi < 4; ++mi)
#pragma unroll
        for (int ni = 0; ni < 4; ++ni)
#pragma unroll
            for (int r = 0; r < 4; ++r) {
                int row = orow0 + mi * 16 + r;
                int col = ocol0 + ni * 16;
                O[(size_t)row * OUT_F + col] = acc[mi][ni][r] + bv[ni];
            }
}

extern "C" void kernel_launch(void* const* d_in, const int* in_sizes, int n_in,
                              void* d_out, int out_size, void* d_ws, size_t ws_size,
                              hipStream_t stream) {
    const float* X  = (const float*)d_in[0];
    const int*   QW = (const int*)d_in[1];
    const int*   QZ = (const int*)d_in[2];
    const float* S  = (const float*)d_in[3];
    const float* Bi = (const float*)d_in[4];
    float*       O  = (float*)d_out;

    if (ws_size >= XSW_BYTES) {
        unsigned short* Xsw = (unsigned short*)d_ws;
        x_convert_kernel<<<dim3(TOKENS * IN_F / 8 / 256), dim3(256), 0, stream>>>(X, Xsw);
        awq_gemm_dma_kernel<<<dim3(8 * NTILES), dim3(512), LDSTOT, stream>>>(
            Xsw, QW, QZ, S, Bi, O);
    } else {
        awq_gemm_fb_kernel<<<dim3(8 * NTILES), dim3(512), 0, stream>>>(X, QW, QZ, S, Bi, O);
    }
}